// Round 11
// baseline (424.036 us; speedup 1.0000x reference)
//
#include <hip/hip_runtime.h>
#include <math.h>

#define N_NODES 50000
#define N_EDGES 1600000
#define N_RELS 8
#define N_BASES 4
#define HD 64

#define NB_D 196                 // ceil(50000/256) blocks in fused projection kernel
#define NB_E 782                 // scatter kernel: 782*256 threads * 2 quads = 400384 >= 400000
#define NTHR_E (NB_E * 256)      // 200192
#define NQUAD (N_EDGES / 4)      // 400000
#define NB_Z 1563                // zero kernel: 1563*256 float4 >= 400000 cells

typedef int   vint4   __attribute__((ext_vector_type(4)));
typedef float vfloat4 __attribute__((ext_vector_type(4)));

// ws layout (floats):
//   G[27][64]   at G_OFF    [0..1728)
//   partials    at PART_OFF [1728..1728+NB_D)
//   T           at T_OFF    r-major fp32 cells: cell (r,v) = 4 floats
//                           (sum_fx, sum_fy, count, pad) at T + (r*N_NODES+v)*4
//                           = 1.6M floats = 6.4 MB
#define G_OFF    0
#define PART_OFF 1728
#define T_OFF    4096
#define T_FLOATS (N_RELS * N_NODES * 4)   // 1,600,000

// ---------------------------------------------------------------------------
// Zero T (all blocks) + build G[27][64] (block 0 only).
__global__ __launch_bounds__(256) void zero_prep_kernel(
        const float* __restrict__ W_in,
        const float* __restrict__ b_in,
        const float* __restrict__ w_comp,
        const float* __restrict__ bases,
        const float* __restrict__ loop_w,
        const float* __restrict__ h_bias,
        float* __restrict__ G,
        vfloat4* __restrict__ T4) {
    const int tid = threadIdx.x;
    const int zi = blockIdx.x * 256 + tid;
    if (zi < T_FLOATS / 4) T4[zi] = (vfloat4){0.f, 0.f, 0.f, 0.f};

    if (blockIdx.x != 0) return;

    __shared__ float sA[N_BASES * 3 * HD];   // A[b][k][o]
    const int o = tid & 63;
    const int b = tid >> 6;                  // 0..3

    // A[b][k][o] = sum_i winrow_k[i] * bases[b,i,o]
    {
        float s0 = 0.f, s1 = 0.f, sb = 0.f;
        for (int i = 0; i < HD; i++) {
            float bv = bases[b * HD * HD + i * HD + o];
            s0 += W_in[i]      * bv;
            s1 += W_in[HD + i] * bv;
            sb += b_in[i]      * bv;
        }
        sA[(b * 3 + 0) * HD + o] = s0;
        sA[(b * 3 + 1) * HD + o] = s1;
        sA[(b * 3 + 2) * HD + o] = sb;
    }
    __syncthreads();

    // G[j][o] = sum_b w_comp[r,b] * A[b][k][o],  j = 3r+k
    for (int idx = tid; idx < 24 * HD; idx += 256) {
        int j = idx >> 6, oo = idx & 63;
        int r = j / 3, k = j % 3;
        float s = 0.f;
#pragma unroll
        for (int bb = 0; bb < N_BASES; bb++)
            s += w_comp[r * N_BASES + bb] * sA[(bb * 3 + k) * HD + oo];
        G[j * HD + oo] = s;
    }

    // self-loop columns j=24,25,26
    if (tid < 3 * HD) {
        int k = tid >> 6, oo = tid & 63;
        float s = 0.f;
        for (int i = 0; i < HD; i++) {
            float w = (k == 0) ? W_in[i] : (k == 1) ? W_in[HD + i] : b_in[i];
            s += w * loop_w[i * HD + oo];
        }
        if (k == 2) s += h_bias[oo];
        G[(24 + k) * HD + oo] = s;
    }
}

// ---------------------------------------------------------------------------
// Edge scatter: ONE gather per edge (feat[src], 400KB L2-hot table) and three
// fire-and-forget fp32 atomic adds into T[etype,dst]: (fx, fy, 1).
// No MSHR/latency exposure on the write path; halves the gather miss count
// vs the gather formulation. Tail quads weighted 0 (atomicAdd of 0 = no-op).
__global__ __launch_bounds__(256) void edge_scatter_kernel(
        const vint4* __restrict__ src4,
        const vint4* __restrict__ dst4,
        const vint4* __restrict__ et4,
        const float2* __restrict__ feat,
        float* __restrict__ T) {
    const int t = blockIdx.x * 256 + threadIdx.x;    // t < 200192 <= NQUAD: always valid
    const int t2raw = t + NTHR_E;
    const int t2 = (t2raw < NQUAD) ? t2raw : (NQUAD - 1);
    const float w2 = (t2raw < NQUAD) ? 1.f : 0.f;

    vint4 uA = __builtin_nontemporal_load(&src4[t]);
    vint4 vA = __builtin_nontemporal_load(&dst4[t]);
    vint4 rA = __builtin_nontemporal_load(&et4[t]);
    vint4 uB = __builtin_nontemporal_load(&src4[t2]);
    vint4 vB = __builtin_nontemporal_load(&dst4[t2]);
    vint4 rB = __builtin_nontemporal_load(&et4[t2]);

    float2 fA0 = feat[uA.x];
    float2 fA1 = feat[uA.y];
    float2 fA2 = feat[uA.z];
    float2 fA3 = feat[uA.w];
    float2 fB0 = feat[uB.x];
    float2 fB1 = feat[uB.y];
    float2 fB2 = feat[uB.z];
    float2 fB3 = feat[uB.w];

    // float index of cell (r,v) = (r*N_NODES + v)*4
    int cA0 = (rA.x * N_NODES + vA.x) * 4;
    int cA1 = (rA.y * N_NODES + vA.y) * 4;
    int cA2 = (rA.z * N_NODES + vA.z) * 4;
    int cA3 = (rA.w * N_NODES + vA.w) * 4;
    int cB0 = (rB.x * N_NODES + vB.x) * 4;
    int cB1 = (rB.y * N_NODES + vB.y) * 4;
    int cB2 = (rB.z * N_NODES + vB.z) * 4;
    int cB3 = (rB.w * N_NODES + vB.w) * 4;

    // unsafeAtomicAdd -> native global_atomic_add_f32 (no CAS loop), result
    // unused -> fire-and-forget.
    unsafeAtomicAdd(&T[cA0 + 0], fA0.x); unsafeAtomicAdd(&T[cA0 + 1], fA0.y); unsafeAtomicAdd(&T[cA0 + 2], 1.f);
    unsafeAtomicAdd(&T[cA1 + 0], fA1.x); unsafeAtomicAdd(&T[cA1 + 1], fA1.y); unsafeAtomicAdd(&T[cA1 + 2], 1.f);
    unsafeAtomicAdd(&T[cA2 + 0], fA2.x); unsafeAtomicAdd(&T[cA2 + 1], fA2.y); unsafeAtomicAdd(&T[cA2 + 2], 1.f);
    unsafeAtomicAdd(&T[cA3 + 0], fA3.x); unsafeAtomicAdd(&T[cA3 + 1], fA3.y); unsafeAtomicAdd(&T[cA3 + 2], 1.f);
    unsafeAtomicAdd(&T[cB0 + 0], w2 * fB0.x); unsafeAtomicAdd(&T[cB0 + 1], w2 * fB0.y); unsafeAtomicAdd(&T[cB0 + 2], w2);
    unsafeAtomicAdd(&T[cB1 + 0], w2 * fB1.x); unsafeAtomicAdd(&T[cB1 + 1], w2 * fB1.y); unsafeAtomicAdd(&T[cB1 + 2], w2);
    unsafeAtomicAdd(&T[cB2 + 0], w2 * fB2.x); unsafeAtomicAdd(&T[cB2 + 1], w2 * fB2.y); unsafeAtomicAdd(&T[cB2 + 2], w2);
    unsafeAtomicAdd(&T[cB3 + 0], w2 * fB3.x); unsafeAtomicAdd(&T[cB3 + 1], w2 * fB3.y); unsafeAtomicAdd(&T[cB3 + 2], w2);
}

// ---------------------------------------------------------------------------
// Fused projection + contraction: per node v compute d_k[r,v] on the fly
// (s[27], as the old d_table did), then dot with the scattered T cells and
// the self-loop term. No D table materialized at all.
__global__ __launch_bounds__(256) void fused_proj_kernel(
        const vfloat4* __restrict__ fcW4,
        const float2* __restrict__ feat,
        const float* __restrict__ G,
        const vfloat4* __restrict__ T4,   // cell (r,v) at index r*N_NODES+v
        float* __restrict__ partD) {
    const int v = blockIdx.x * 256 + threadIdx.x;
    float part = 0.f;

    if (v < N_NODES) {
        vfloat4 Fr[16];
#pragma unroll
        for (int k = 0; k < 16; k++) Fr[k] = __builtin_nontemporal_load(&fcW4[v * 16 + k]);

        float s[27];
#pragma unroll
        for (int j = 0; j < 27; j++) {
            float acc = 0.f;
#pragma unroll
            for (int k = 0; k < 16; k++) {
                // uniform addresses -> scalar loads, broadcast
                float gx = G[j * HD + 4 * k + 0];
                float gy = G[j * HD + 4 * k + 1];
                float gz = G[j * HD + 4 * k + 2];
                float gw = G[j * HD + 4 * k + 3];
                acc += Fr[k].x * gx + Fr[k].y * gy + Fr[k].z * gz + Fr[k].w * gw;
            }
            s[j] = acc;
        }

        // relation part: T[r,v] · (d0,d1,d2)[r,v]  (coalesced float4 loads)
#pragma unroll
        for (int r = 0; r < N_RELS; r++) {
            vfloat4 Tc = T4[r * N_NODES + v];
            part += Tc.x * s[3 * r] + Tc.y * s[3 * r + 1] + Tc.z * s[3 * r + 2];
        }

        // self-loop part
        float2 f = feat[v];
        part += s[24] * f.x + s[25] * f.y + s[26];
    }

    // shuffle block reduce (wave64), single barrier
    for (int off = 32; off; off >>= 1) part += __shfl_down(part, off);
    __shared__ float wred[4];
    if ((threadIdx.x & 63) == 0) wred[threadIdx.x >> 6] = part;
    __syncthreads();
    if (threadIdx.x == 0) partD[blockIdx.x] = wred[0] + wred[1] + wred[2] + wred[3];
}

// ---------------------------------------------------------------------------
// 1-block final reduce over 196 partials + bias + sigmoid.
__global__ void final_kernel(const float* __restrict__ part,
                             const float* __restrict__ fc_b,
                             float* __restrict__ out) {
    float s = 0.f;
    for (int i = threadIdx.x; i < NB_D; i += 256) s += part[i];
    for (int off = 32; off; off >>= 1) s += __shfl_down(s, off);
    __shared__ float wred[4];
    if ((threadIdx.x & 63) == 0) wred[threadIdx.x >> 6] = s;
    __syncthreads();
    if (threadIdx.x == 0) {
        float x = wred[0] + wred[1] + wred[2] + wred[3] + fc_b[0];
        out[0] = 1.0f / (1.0f + expf(-x));
    }
}

// ---------------------------------------------------------------------------
extern "C" void kernel_launch(void* const* d_in, const int* in_sizes, int n_in,
                              void* d_out, int out_size, void* d_ws, size_t ws_size,
                              hipStream_t stream) {
    const float* features = (const float*)d_in[0];
    const int*   src      = (const int*)d_in[1];
    const int*   dst      = (const int*)d_in[2];
    const int*   etype    = (const int*)d_in[3];
    const float* W_in     = (const float*)d_in[4];
    const float* b_in     = (const float*)d_in[5];
    const float* w_comp   = (const float*)d_in[6];
    const float* bases    = (const float*)d_in[7];
    const float* loop_w   = (const float*)d_in[8];
    const float* h_bias   = (const float*)d_in[9];
    const float* fc_W     = (const float*)d_in[10];
    const float* fc_b     = (const float*)d_in[11];

    float* ws   = (float*)d_ws;
    float* G    = ws + G_OFF;
    float* part = ws + PART_OFF;
    float* T    = ws + T_OFF;
    float* out  = (float*)d_out;

    zero_prep_kernel<<<NB_Z, 256, 0, stream>>>(
        W_in, b_in, w_comp, bases, loop_w, h_bias, G, (vfloat4*)T);
    edge_scatter_kernel<<<NB_E, 256, 0, stream>>>(
        (const vint4*)src, (const vint4*)dst, (const vint4*)etype,
        (const float2*)features, T);
    fused_proj_kernel<<<NB_D, 256, 0, stream>>>(
        (const vfloat4*)fc_W, (const float2*)features, G, (const vfloat4*)T, part);
    final_kernel<<<1, 256, 0, stream>>>(part, fc_b, out);
}

// Round 15
// 144.367 us; speedup vs baseline: 2.9372x; 2.9372x over previous
//
#include <hip/hip_runtime.h>
#include <math.h>

#define N_NODES 50000
#define N_EDGES 1600000
#define N_RELS 8
#define N_BASES 4
#define HD 64

#define NB_D 196                 // ceil(50000/256) blocks in d_table_kernel
#define NB_E 391                 // edge kernel: 391*256 threads * 4 quads = 400384 >= 400000
#define NTHR_E (NB_E * 256)      // 100096
#define NQUAD (N_EDGES / 4)      // 400000

typedef int      vint4   __attribute__((ext_vector_type(4)));
typedef float    vfloat4 __attribute__((ext_vector_type(4)));
typedef _Float16 half4v  __attribute__((ext_vector_type(4)));   // 8B: one (v,r) D entry
typedef _Float16 half8v  __attribute__((ext_vector_type(8)));   // 16B: two entries (store side)

// ws layout (floats):
//   G[27][64]   at G_OFF      [0..1728)
//   partials    at PART_OFF   [1728..1728+NB_D+NB_E)
//   D           at D_OFF      v-major fp16: half4v index = v*8 + r
//                             (d0,d1,d2,0) per (v,r) -> 8B, 64B per node, 3.2 MB total
#define G_OFF      0
#define PART_OFF   1728
#define D_OFF      4096

// ---------------------------------------------------------------------------
// Build G[27][64]. One 256-thread block.
__global__ void prep_kernel(const float* __restrict__ W_in,
                            const float* __restrict__ b_in,
                            const float* __restrict__ w_comp,
                            const float* __restrict__ bases,
                            const float* __restrict__ loop_w,
                            const float* __restrict__ h_bias,
                            float* __restrict__ G) {
    __shared__ float sA[N_BASES * 3 * HD];   // A[b][k][o]
    const int tid = threadIdx.x;
    const int o = tid & 63;
    const int b = tid >> 6;                  // 0..3

    // A[b][k][o] = sum_i winrow_k[i] * bases[b,i,o]
    {
        float s0 = 0.f, s1 = 0.f, sb = 0.f;
        for (int i = 0; i < HD; i++) {
            float bv = bases[b * HD * HD + i * HD + o];
            s0 += W_in[i]      * bv;
            s1 += W_in[HD + i] * bv;
            sb += b_in[i]      * bv;
        }
        sA[(b * 3 + 0) * HD + o] = s0;
        sA[(b * 3 + 1) * HD + o] = s1;
        sA[(b * 3 + 2) * HD + o] = sb;
    }
    __syncthreads();

    // G[j][o] = sum_b w_comp[r,b] * A[b][k][o],  j = 3r+k
    for (int idx = tid; idx < 24 * HD; idx += 256) {
        int j = idx >> 6, oo = idx & 63;
        int r = j / 3, k = j % 3;
        float s = 0.f;
#pragma unroll
        for (int bb = 0; bb < N_BASES; bb++)
            s += w_comp[r * N_BASES + bb] * sA[(bb * 3 + k) * HD + oo];
        G[j * HD + oo] = s;
    }

    // self-loop columns j=24,25,26
    if (tid < 3 * HD) {
        int k = tid >> 6, oo = tid & 63;
        float s = 0.f;
        for (int i = 0; i < HD; i++) {
            float w = (k == 0) ? W_in[i] : (k == 1) ? W_in[HD + i] : b_in[i];
            s += w * loop_w[i * HD + oo];
        }
        if (k == 2) s += h_bias[oo];
        G[(24 + k) * HD + oo] = s;
    }
}

// ---------------------------------------------------------------------------
// D entry (v,r) = (fcW_v·g_{r,0}, fcW_v·g_{r,1}, fcW_v·g_{r,2}, 0) in fp16,
// v-major so each node's 8 relations share one 64B line.
// fc_W is a 12.8 MB one-shot stream -> nontemporal, keep L2 for D.
__global__ __launch_bounds__(256) void d_table_kernel(
        const vfloat4* __restrict__ fcW4,
        const float2* __restrict__ feat,
        const float* __restrict__ G,
        half8v* __restrict__ D16,        // index v*4 + j  (rel pair j)
        float* __restrict__ partD) {
    const int v = blockIdx.x * 256 + threadIdx.x;
    float part = 0.f;

    if (v < N_NODES) {
        vfloat4 Fr[16];
#pragma unroll
        for (int k = 0; k < 16; k++) Fr[k] = __builtin_nontemporal_load(&fcW4[v * 16 + k]);

        float s[27];
#pragma unroll
        for (int j = 0; j < 27; j++) {
            float acc = 0.f;
#pragma unroll
            for (int k = 0; k < 16; k++) {
                // uniform addresses -> scalar loads, broadcast
                float gx = G[j * HD + 4 * k + 0];
                float gy = G[j * HD + 4 * k + 1];
                float gz = G[j * HD + 4 * k + 2];
                float gw = G[j * HD + 4 * k + 3];
                acc += Fr[k].x * gx + Fr[k].y * gy + Fr[k].z * gz + Fr[k].w * gw;
            }
            s[j] = acc;
        }

        // pack rels (2j, 2j+1) into one 16B store; node v occupies D16[v*4 .. v*4+4)
#pragma unroll
        for (int j = 0; j < 4; j++) {
            half8v pk;
            pk[0] = (_Float16)s[6 * j + 0];
            pk[1] = (_Float16)s[6 * j + 1];
            pk[2] = (_Float16)s[6 * j + 2];
            pk[3] = (_Float16)0.f;
            pk[4] = (_Float16)s[6 * j + 3];
            pk[5] = (_Float16)s[6 * j + 4];
            pk[6] = (_Float16)s[6 * j + 5];
            pk[7] = (_Float16)0.f;
            D16[v * 4 + j] = pk;
        }

        float2 f = feat[v];
        part = s[24] * f.x + s[25] * f.y + s[26];
    }

    // shuffle block reduce (wave64), single barrier
    for (int off = 32; off; off >>= 1) part += __shfl_down(part, off);
    __shared__ float wred[4];
    if ((threadIdx.x & 63) == 0) wred[threadIdx.x >> 6] = part;
    __syncthreads();
    if (threadIdx.x == 0) partD[blockIdx.x] = wred[0] + wred[1] + wred[2] + wred[3];
}

// ---------------------------------------------------------------------------
// Pure gather over edges: 4 quads per thread, straight-line (branch-free
// clamped tail on quad D only) -> 44 loads in flight per lane. fp16 D gathers
// (8B) from a 3.2 MB L2-resident table. One partial per block.
__global__ __launch_bounds__(256) void edge_gather_kernel(
        const vint4* __restrict__ src4,
        const vint4* __restrict__ dst4,
        const vint4* __restrict__ et4,
        const float2* __restrict__ feat,
        const half4v* __restrict__ D8,  // index v*8 + r
        float* __restrict__ partE) {
    const int t = blockIdx.x * 256 + threadIdx.x;
    const int qA = t;                    // < 100096 <= NQUAD: valid
    const int qB = t + NTHR_E;           // < 200192: valid
    const int qC = t + 2 * NTHR_E;       // < 300288: valid
    const int qDraw = t + 3 * NTHR_E;    // may exceed 400000
    const int qD = (qDraw < NQUAD) ? qDraw : (NQUAD - 1);
    const float wD = (qDraw < NQUAD) ? 1.f : 0.f;

    vint4 uA = __builtin_nontemporal_load(&src4[qA]);
    vint4 vA = __builtin_nontemporal_load(&dst4[qA]);
    vint4 rA = __builtin_nontemporal_load(&et4[qA]);
    vint4 uB = __builtin_nontemporal_load(&src4[qB]);
    vint4 vB = __builtin_nontemporal_load(&dst4[qB]);
    vint4 rB = __builtin_nontemporal_load(&et4[qB]);
    vint4 uC = __builtin_nontemporal_load(&src4[qC]);
    vint4 vC = __builtin_nontemporal_load(&dst4[qC]);
    vint4 rC = __builtin_nontemporal_load(&et4[qC]);
    vint4 uD = __builtin_nontemporal_load(&src4[qD]);
    vint4 vD = __builtin_nontemporal_load(&dst4[qD]);
    vint4 rD = __builtin_nontemporal_load(&et4[qD]);

    float2 fA0 = feat[uA.x], fA1 = feat[uA.y], fA2 = feat[uA.z], fA3 = feat[uA.w];
    float2 fB0 = feat[uB.x], fB1 = feat[uB.y], fB2 = feat[uB.z], fB3 = feat[uB.w];
    float2 fC0 = feat[uC.x], fC1 = feat[uC.y], fC2 = feat[uC.z], fC3 = feat[uC.w];
    float2 fD0 = feat[uD.x], fD1 = feat[uD.y], fD2 = feat[uD.z], fD3 = feat[uD.w];

    half4v hA0 = D8[vA.x * 8 + rA.x], hA1 = D8[vA.y * 8 + rA.y];
    half4v hA2 = D8[vA.z * 8 + rA.z], hA3 = D8[vA.w * 8 + rA.w];
    half4v hB0 = D8[vB.x * 8 + rB.x], hB1 = D8[vB.y * 8 + rB.y];
    half4v hB2 = D8[vB.z * 8 + rB.z], hB3 = D8[vB.w * 8 + rB.w];
    half4v hC0 = D8[vC.x * 8 + rC.x], hC1 = D8[vC.y * 8 + rC.y];
    half4v hC2 = D8[vC.z * 8 + rC.z], hC3 = D8[vC.w * 8 + rC.w];
    half4v hD0 = D8[vD.x * 8 + rD.x], hD1 = D8[vD.y * 8 + rD.y];
    half4v hD2 = D8[vD.z * 8 + rD.z], hD3 = D8[vD.w * 8 + rD.w];

    float sA = fA0.x * (float)hA0.x + fA0.y * (float)hA0.y + (float)hA0.z;
    sA      += fA1.x * (float)hA1.x + fA1.y * (float)hA1.y + (float)hA1.z;
    sA      += fA2.x * (float)hA2.x + fA2.y * (float)hA2.y + (float)hA2.z;
    sA      += fA3.x * (float)hA3.x + fA3.y * (float)hA3.y + (float)hA3.z;
    float sB = fB0.x * (float)hB0.x + fB0.y * (float)hB0.y + (float)hB0.z;
    sB      += fB1.x * (float)hB1.x + fB1.y * (float)hB1.y + (float)hB1.z;
    sB      += fB2.x * (float)hB2.x + fB2.y * (float)hB2.y + (float)hB2.z;
    sB      += fB3.x * (float)hB3.x + fB3.y * (float)hB3.y + (float)hB3.z;
    float sC = fC0.x * (float)hC0.x + fC0.y * (float)hC0.y + (float)hC0.z;
    sC      += fC1.x * (float)hC1.x + fC1.y * (float)hC1.y + (float)hC1.z;
    sC      += fC2.x * (float)hC2.x + fC2.y * (float)hC2.y + (float)hC2.z;
    sC      += fC3.x * (float)hC3.x + fC3.y * (float)hC3.y + (float)hC3.z;
    float sD = fD0.x * (float)hD0.x + fD0.y * (float)hD0.y + (float)hD0.z;
    sD      += fD1.x * (float)hD1.x + fD1.y * (float)hD1.y + (float)hD1.z;
    sD      += fD2.x * (float)hD2.x + fD2.y * (float)hD2.y + (float)hD2.z;
    sD      += fD3.x * (float)hD3.x + fD3.y * (float)hD3.y + (float)hD3.z;
    float s = (sA + sB) + (sC + wD * sD);

    // shuffle block reduce (wave64), single barrier
    for (int off = 32; off; off >>= 1) s += __shfl_down(s, off);
    __shared__ float wred[4];
    if ((threadIdx.x & 63) == 0) wred[threadIdx.x >> 6] = s;
    __syncthreads();
    if (threadIdx.x == 0) partE[blockIdx.x] = wred[0] + wred[1] + wred[2] + wred[3];
}

// ---------------------------------------------------------------------------
// Separate 1-block final reduce: inter-dispatch ordering guarantees
// visibility of all partials — no fences/atomics needed.
__global__ void final_kernel(const float* __restrict__ part,
                             const float* __restrict__ fc_b,
                             float* __restrict__ out) {
    float s = 0.f;
    for (int i = threadIdx.x; i < NB_D + NB_E; i += 256) s += part[i];
    for (int off = 32; off; off >>= 1) s += __shfl_down(s, off);
    __shared__ float wred[4];
    if ((threadIdx.x & 63) == 0) wred[threadIdx.x >> 6] = s;
    __syncthreads();
    if (threadIdx.x == 0) {
        float x = wred[0] + wred[1] + wred[2] + wred[3] + fc_b[0];
        out[0] = 1.0f / (1.0f + expf(-x));
    }
}

// ---------------------------------------------------------------------------
extern "C" void kernel_launch(void* const* d_in, const int* in_sizes, int n_in,
                              void* d_out, int out_size, void* d_ws, size_t ws_size,
                              hipStream_t stream) {
    const float* features = (const float*)d_in[0];
    const int*   src      = (const int*)d_in[1];
    const int*   dst      = (const int*)d_in[2];
    const int*   etype    = (const int*)d_in[3];
    const float* W_in     = (const float*)d_in[4];
    const float* b_in     = (const float*)d_in[5];
    const float* w_comp   = (const float*)d_in[6];
    const float* bases    = (const float*)d_in[7];
    const float* loop_w   = (const float*)d_in[8];
    const float* h_bias   = (const float*)d_in[9];
    const float* fc_W     = (const float*)d_in[10];
    const float* fc_b     = (const float*)d_in[11];

    float* ws   = (float*)d_ws;
    float* G    = ws + G_OFF;
    float* part = ws + PART_OFF;
    half8v* D16 = (half8v*)(ws + D_OFF);
    half4v* D8  = (half4v*)(ws + D_OFF);
    float* out  = (float*)d_out;

    prep_kernel<<<1, 256, 0, stream>>>(W_in, b_in, w_comp, bases, loop_w, h_bias, G);
    d_table_kernel<<<NB_D, 256, 0, stream>>>(
        (const vfloat4*)fc_W, (const float2*)features, G, D16, part);
    edge_gather_kernel<<<NB_E, 256, 0, stream>>>(
        (const vint4*)src, (const vint4*)dst, (const vint4*)etype,
        (const float2*)features, D8, part + NB_D);
    final_kernel<<<1, 256, 0, stream>>>(part, fc_b, out);
}

// Round 16
// 140.558 us; speedup vs baseline: 3.0168x; 1.0271x over previous
//
#include <hip/hip_runtime.h>
#include <math.h>

#define N_NODES 50000
#define N_EDGES 1600000
#define N_RELS 8
#define N_BASES 4
#define HD 64

#define NB_D 196                 // ceil(50000/256) blocks in d_table_kernel
#define NB_E 391                 // edge kernel: 391*256 threads * 4 quads = 400384 >= 400000
#define NTHR_E (NB_E * 256)      // 100096
#define NQUAD (N_EDGES / 4)      // 400000

typedef int      vint4   __attribute__((ext_vector_type(4)));
typedef float    vfloat4 __attribute__((ext_vector_type(4)));
typedef _Float16 half4v  __attribute__((ext_vector_type(4)));   // 8B: one (v,r) D entry
typedef _Float16 half8v  __attribute__((ext_vector_type(8)));   // 16B: two entries (store side)

// ws layout (floats):
//   partials    at PART_OFF   [0..NB_D+NB_E)
//   D           at D_OFF      v-major fp16: half4v index = v*8 + r
//                             (d0,d1,d2,0) per (v,r) -> 8B, 64B per node, 3.2 MB total
#define PART_OFF   0
#define D_OFF      4096

// ---------------------------------------------------------------------------
// Fused: per-block G build (in LDS) + D-table projection.
// Every block redundantly computes G[27][64] from the tiny weight tensors
// (bases et al. are L2-resident after block 0) -> no separate prep launch,
// and the hot G reads become LDS broadcasts instead of L2 scalar loads.
__global__ __launch_bounds__(256) void d_table_kernel(
        const float* __restrict__ W_in,
        const float* __restrict__ b_in,
        const float* __restrict__ w_comp,
        const float* __restrict__ bases,
        const float* __restrict__ loop_w,
        const float* __restrict__ h_bias,
        const vfloat4* __restrict__ fcW4,
        const float2* __restrict__ feat,
        half8v* __restrict__ D16,        // index v*4 + j  (rel pair j)
        float* __restrict__ partD) {
    __shared__ float sA[N_BASES * 3 * HD];   // A[b][k][o]
    __shared__ float sG[27 * HD];            // G[j][o]
    const int tid = threadIdx.x;

    // ---- G build (identical math to the old prep_kernel, LDS-resident) ----
    {
        const int o = tid & 63;
        const int b = tid >> 6;              // 0..3
        float s0 = 0.f, s1 = 0.f, sb = 0.f;
        for (int i = 0; i < HD; i++) {
            float bv = bases[b * HD * HD + i * HD + o];
            s0 += W_in[i]      * bv;
            s1 += W_in[HD + i] * bv;
            sb += b_in[i]      * bv;
        }
        sA[(b * 3 + 0) * HD + o] = s0;
        sA[(b * 3 + 1) * HD + o] = s1;
        sA[(b * 3 + 2) * HD + o] = sb;
    }
    __syncthreads();

    for (int idx = tid; idx < 24 * HD; idx += 256) {
        int j = idx >> 6, oo = idx & 63;
        int r = j / 3, k = j % 3;
        float s = 0.f;
#pragma unroll
        for (int bb = 0; bb < N_BASES; bb++)
            s += w_comp[r * N_BASES + bb] * sA[(bb * 3 + k) * HD + oo];
        sG[j * HD + oo] = s;
    }
    if (tid < 3 * HD) {
        int k = tid >> 6, oo = tid & 63;
        float s = 0.f;
        for (int i = 0; i < HD; i++) {
            float w = (k == 0) ? W_in[i] : (k == 1) ? W_in[HD + i] : b_in[i];
            s += w * loop_w[i * HD + oo];
        }
        if (k == 2) s += h_bias[oo];
        sG[(24 + k) * HD + oo] = s;
    }
    __syncthreads();

    // ---- D-table projection (same as measured r5/r15 kernel) ----
    const int v = blockIdx.x * 256 + tid;
    float part = 0.f;

    if (v < N_NODES) {
        vfloat4 Fr[16];
#pragma unroll
        for (int k = 0; k < 16; k++) Fr[k] = __builtin_nontemporal_load(&fcW4[v * 16 + k]);

        float s[27];
#pragma unroll
        for (int j = 0; j < 27; j++) {
            float acc = 0.f;
#pragma unroll
            for (int k = 0; k < 16; k++) {
                // uniform LDS addresses -> broadcast reads, conflict-free
                float gx = sG[j * HD + 4 * k + 0];
                float gy = sG[j * HD + 4 * k + 1];
                float gz = sG[j * HD + 4 * k + 2];
                float gw = sG[j * HD + 4 * k + 3];
                acc += Fr[k].x * gx + Fr[k].y * gy + Fr[k].z * gz + Fr[k].w * gw;
            }
            s[j] = acc;
        }

        // pack rels (2j, 2j+1) into one 16B store; node v occupies D16[v*4 .. v*4+4)
#pragma unroll
        for (int j = 0; j < 4; j++) {
            half8v pk;
            pk[0] = (_Float16)s[6 * j + 0];
            pk[1] = (_Float16)s[6 * j + 1];
            pk[2] = (_Float16)s[6 * j + 2];
            pk[3] = (_Float16)0.f;
            pk[4] = (_Float16)s[6 * j + 3];
            pk[5] = (_Float16)s[6 * j + 4];
            pk[6] = (_Float16)s[6 * j + 5];
            pk[7] = (_Float16)0.f;
            D16[v * 4 + j] = pk;
        }

        float2 f = feat[v];
        part = s[24] * f.x + s[25] * f.y + s[26];
    }

    // shuffle block reduce (wave64), single barrier
    for (int off = 32; off; off >>= 1) part += __shfl_down(part, off);
    __shared__ float wred[4];
    if ((threadIdx.x & 63) == 0) wred[threadIdx.x >> 6] = part;
    __syncthreads();
    if (threadIdx.x == 0) partD[blockIdx.x] = wred[0] + wred[1] + wred[2] + wred[3];
}

// ---------------------------------------------------------------------------
// Pure gather over edges: 4 quads per thread, straight-line (branch-free
// clamped tail on quad D only) -> 44 loads in flight per lane. fp16 D gathers
// (8B) from a 3.2 MB L2-resident table. One partial per block.
// (Measured: 2-quad ~43 µs, 4-quad ~2 µs faster total -> MSHR-capped.)
__global__ __launch_bounds__(256) void edge_gather_kernel(
        const vint4* __restrict__ src4,
        const vint4* __restrict__ dst4,
        const vint4* __restrict__ et4,
        const float2* __restrict__ feat,
        const half4v* __restrict__ D8,  // index v*8 + r
        float* __restrict__ partE) {
    const int t = blockIdx.x * 256 + threadIdx.x;
    const int qA = t;                    // < 100096 <= NQUAD: valid
    const int qB = t + NTHR_E;           // < 200192: valid
    const int qC = t + 2 * NTHR_E;       // < 300288: valid
    const int qDraw = t + 3 * NTHR_E;    // may exceed 400000
    const int qD = (qDraw < NQUAD) ? qDraw : (NQUAD - 1);
    const float wD = (qDraw < NQUAD) ? 1.f : 0.f;

    vint4 uA = __builtin_nontemporal_load(&src4[qA]);
    vint4 vA = __builtin_nontemporal_load(&dst4[qA]);
    vint4 rA = __builtin_nontemporal_load(&et4[qA]);
    vint4 uB = __builtin_nontemporal_load(&src4[qB]);
    vint4 vB = __builtin_nontemporal_load(&dst4[qB]);
    vint4 rB = __builtin_nontemporal_load(&et4[qB]);
    vint4 uC = __builtin_nontemporal_load(&src4[qC]);
    vint4 vC = __builtin_nontemporal_load(&dst4[qC]);
    vint4 rC = __builtin_nontemporal_load(&et4[qC]);
    vint4 uD = __builtin_nontemporal_load(&src4[qD]);
    vint4 vD = __builtin_nontemporal_load(&dst4[qD]);
    vint4 rD = __builtin_nontemporal_load(&et4[qD]);

    float2 fA0 = feat[uA.x], fA1 = feat[uA.y], fA2 = feat[uA.z], fA3 = feat[uA.w];
    float2 fB0 = feat[uB.x], fB1 = feat[uB.y], fB2 = feat[uB.z], fB3 = feat[uB.w];
    float2 fC0 = feat[uC.x], fC1 = feat[uC.y], fC2 = feat[uC.z], fC3 = feat[uC.w];
    float2 fD0 = feat[uD.x], fD1 = feat[uD.y], fD2 = feat[uD.z], fD3 = feat[uD.w];

    half4v hA0 = D8[vA.x * 8 + rA.x], hA1 = D8[vA.y * 8 + rA.y];
    half4v hA2 = D8[vA.z * 8 + rA.z], hA3 = D8[vA.w * 8 + rA.w];
    half4v hB0 = D8[vB.x * 8 + rB.x], hB1 = D8[vB.y * 8 + rB.y];
    half4v hB2 = D8[vB.z * 8 + rB.z], hB3 = D8[vB.w * 8 + rB.w];
    half4v hC0 = D8[vC.x * 8 + rC.x], hC1 = D8[vC.y * 8 + rC.y];
    half4v hC2 = D8[vC.z * 8 + rC.z], hC3 = D8[vC.w * 8 + rC.w];
    half4v hD0 = D8[vD.x * 8 + rD.x], hD1 = D8[vD.y * 8 + rD.y];
    half4v hD2 = D8[vD.z * 8 + rD.z], hD3 = D8[vD.w * 8 + rD.w];

    float sA = fA0.x * (float)hA0.x + fA0.y * (float)hA0.y + (float)hA0.z;
    sA      += fA1.x * (float)hA1.x + fA1.y * (float)hA1.y + (float)hA1.z;
    sA      += fA2.x * (float)hA2.x + fA2.y * (float)hA2.y + (float)hA2.z;
    sA      += fA3.x * (float)hA3.x + fA3.y * (float)hA3.y + (float)hA3.z;
    float sB = fB0.x * (float)hB0.x + fB0.y * (float)hB0.y + (float)hB0.z;
    sB      += fB1.x * (float)hB1.x + fB1.y * (float)hB1.y + (float)hB1.z;
    sB      += fB2.x * (float)hB2.x + fB2.y * (float)hB2.y + (float)hB2.z;
    sB      += fB3.x * (float)hB3.x + fB3.y * (float)hB3.y + (float)hB3.z;
    float sC = fC0.x * (float)hC0.x + fC0.y * (float)hC0.y + (float)hC0.z;
    sC      += fC1.x * (float)hC1.x + fC1.y * (float)hC1.y + (float)hC1.z;
    sC      += fC2.x * (float)hC2.x + fC2.y * (float)hC2.y + (float)hC2.z;
    sC      += fC3.x * (float)hC3.x + fC3.y * (float)hC3.y + (float)hC3.z;
    float sD = fD0.x * (float)hD0.x + fD0.y * (float)hD0.y + (float)hD0.z;
    sD      += fD1.x * (float)hD1.x + fD1.y * (float)hD1.y + (float)hD1.z;
    sD      += fD2.x * (float)hD2.x + fD2.y * (float)hD2.y + (float)hD2.z;
    sD      += fD3.x * (float)hD3.x + fD3.y * (float)hD3.y + (float)hD3.z;
    float s = (sA + sB) + (sC + wD * sD);

    // shuffle block reduce (wave64), single barrier
    for (int off = 32; off; off >>= 1) s += __shfl_down(s, off);
    __shared__ float wred[4];
    if ((threadIdx.x & 63) == 0) wred[threadIdx.x >> 6] = s;
    __syncthreads();
    if (threadIdx.x == 0) partE[blockIdx.x] = wred[0] + wred[1] + wred[2] + wred[3];
}

// ---------------------------------------------------------------------------
// Separate 1-block final reduce: inter-dispatch ordering guarantees
// visibility of all partials — no fences/atomics needed.
__global__ void final_kernel(const float* __restrict__ part,
                             const float* __restrict__ fc_b,
                             float* __restrict__ out) {
    float s = 0.f;
    for (int i = threadIdx.x; i < NB_D + NB_E; i += 256) s += part[i];
    for (int off = 32; off; off >>= 1) s += __shfl_down(s, off);
    __shared__ float wred[4];
    if ((threadIdx.x & 63) == 0) wred[threadIdx.x >> 6] = s;
    __syncthreads();
    if (threadIdx.x == 0) {
        float x = wred[0] + wred[1] + wred[2] + wred[3] + fc_b[0];
        out[0] = 1.0f / (1.0f + expf(-x));
    }
}

// ---------------------------------------------------------------------------
extern "C" void kernel_launch(void* const* d_in, const int* in_sizes, int n_in,
                              void* d_out, int out_size, void* d_ws, size_t ws_size,
                              hipStream_t stream) {
    const float* features = (const float*)d_in[0];
    const int*   src      = (const int*)d_in[1];
    const int*   dst      = (const int*)d_in[2];
    const int*   etype    = (const int*)d_in[3];
    const float* W_in     = (const float*)d_in[4];
    const float* b_in     = (const float*)d_in[5];
    const float* w_comp   = (const float*)d_in[6];
    const float* bases    = (const float*)d_in[7];
    const float* loop_w   = (const float*)d_in[8];
    const float* h_bias   = (const float*)d_in[9];
    const float* fc_W     = (const float*)d_in[10];
    const float* fc_b     = (const float*)d_in[11];

    float* ws   = (float*)d_ws;
    float* part = ws + PART_OFF;
    half8v* D16 = (half8v*)(ws + D_OFF);
    half4v* D8  = (half4v*)(ws + D_OFF);
    float* out  = (float*)d_out;

    d_table_kernel<<<NB_D, 256, 0, stream>>>(
        W_in, b_in, w_comp, bases, loop_w, h_bias,
        (const vfloat4*)fc_W, (const float2*)features, D16, part);
    edge_gather_kernel<<<NB_E, 256, 0, stream>>>(
        (const vint4*)src, (const vint4*)dst, (const vint4*)etype,
        (const float2*)features, D8, part + NB_D);
    final_kernel<<<1, 256, 0, stream>>>(part, fc_b, out);
}